// Round 2
// baseline (836.028 us; speedup 1.0000x reference)
//
#include <hip/hip_runtime.h>

typedef unsigned int u32;
typedef unsigned short u16;
using v4f    = __attribute__((ext_vector_type(4))) float;
using short8 = __attribute__((ext_vector_type(8))) short;

#define GAS __attribute__((address_space(1)))
#define LAS __attribute__((address_space(3)))

// ---- bf16 helpers (RNE, matches HW convert; inputs are finite) ----
__device__ __forceinline__ u16 f2bf(float f){
  u32 u = __builtin_bit_cast(u32, f);
  u32 r = (u + 0x7fffu + ((u >> 16) & 1u)) >> 16;
  return (u16)r;
}
__device__ __forceinline__ float bf2f(u16 h){
  u32 u = ((u32)h) << 16;
  return __builtin_bit_cast(float, u);
}

// async global->LDS, 16B per lane. LDS dest must be wave-uniform base + lane*16;
// staging maps thread t -> chunk t + i*256, so per-wave LDS offsets are
// contiguous (the supported pattern).
__device__ __forceinline__ void gld_lds16(const void* g, void* l){
  __builtin_amdgcn_global_load_lds((const GAS u32*)g, (LAS u32*)l, 16, 0, 0);
}

// ---- transpose fp32 [K][N] -> bf16 [N][K] (weights only) ----
__global__ __launch_bounds__(256) void transpose_w_bf16(
    const float* __restrict__ in, u16* __restrict__ out, int K, int N)
{
  __shared__ float t[64][65];   // +1 pad: conflict-free column reads
  const int k0 = blockIdx.x * 64, n0 = blockIdx.y * 64;
  const int tx = threadIdx.x & 63, ty = threadIdx.x >> 6;
  #pragma unroll
  for (int i = 0; i < 16; i++){
    int r = ty + i * 4;
    t[r][tx] = in[(size_t)(k0 + r) * N + (n0 + tx)];
  }
  __syncthreads();
  #pragma unroll
  for (int i = 0; i < 16; i++){
    int r = ty + i * 4;
    out[(size_t)(n0 + r) * K + (k0 + tx)] = f2bf(t[tx][r]);
  }
}

// ---- in-place row softmax over 2048 bf16 elements, one block per row ----
__global__ __launch_bounds__(256) void softmax_rows(u16* __restrict__ S){
  const int tid = threadIdx.x;
  u16* p = S + (size_t)blockIdx.x * 2048;
  uint4 u = ((const uint4*)p)[tid];
  u32 w[4] = {u.x, u.y, u.z, u.w};
  float f[8];
  #pragma unroll
  for (int i = 0; i < 4; i++){
    f[2*i]   = bf2f((u16)(w[i] & 0xffffu));
    f[2*i+1] = bf2f((u16)(w[i] >> 16));
  }
  float m = f[0];
  #pragma unroll
  for (int i = 1; i < 8; i++) m = fmaxf(m, f[i]);
  #pragma unroll
  for (int o = 32; o >= 1; o >>= 1) m = fmaxf(m, __shfl_xor(m, o));
  __shared__ float redm[4], reds[4];
  if ((tid & 63) == 0) redm[tid >> 6] = m;
  __syncthreads();
  m = fmaxf(fmaxf(redm[0], redm[1]), fmaxf(redm[2], redm[3]));
  float s = 0.f;
  #pragma unroll
  for (int i = 0; i < 8; i++){ f[i] = __expf(f[i] - m); s += f[i]; }
  #pragma unroll
  for (int o = 32; o >= 1; o >>= 1) s += __shfl_xor(s, o);
  if ((tid & 63) == 0) reds[tid >> 6] = s;
  __syncthreads();
  s = reds[0] + reds[1] + reds[2] + reds[3];
  float inv = 1.f / s;
  #pragma unroll
  for (int i = 0; i < 4; i++)
    w[i] = (u32)f2bf(f[2*i] * inv) | ((u32)f2bf(f[2*i+1] * inv) << 16);
  ((uint4*)p)[tid] = make_uint4(w[0], w[1], w[2], w[3]);
}

// ---- 128x128x64 bf16 MFMA GEMM: C = A * BT^T (BT is [N][K] row-major) ----
// AMODE: 0 = A fp32 global (convert in staging), 1 = A bf16, 2 = A concat(qp,x) bf16
// EPI:   0 = +bias[col], store bf16        1 = *scale, store bf16
//        2 = gate: out = x*mask*sigmoid(acc+bg) + q0, store fp32
//        3 = +bias[col], store bf16 TRANSPOSED into [batch][col][rowlocal]
//            (batch = row>>11, rowlocal = row&2047; 4 rows packed per 8B store)
template<int AMODE, int EPI>
__global__ __launch_bounds__(256) void gemm128(
    const float* __restrict__ Af,
    const u16* __restrict__ Ab,
    const u16* __restrict__ A2b,
    const u16* __restrict__ BT,
    int lda, int ldb, int K,
    void* __restrict__ Cout, int ldc,
    const float* __restrict__ bias, float scale,
    size_t aBatch, size_t bBatch, size_t cBatch,
    const u16* __restrict__ xg,
    const float* __restrict__ maskp,
    const float* __restrict__ q0p)
{
  constexpr int BM = 128, BN = 128, BK = 64;
  __shared__ __align__(16) u16 As[BM * BK];   // [m][k]
  __shared__ __align__(16) u16 Bs[BN * BK];   // [n][k]  (B^T tile)
  const int z   = blockIdx.z;
  const int m0  = blockIdx.y * BM, n0 = blockIdx.x * BN;
  const int tid = threadIdx.x;
  const int lane = tid & 63, wid = tid >> 6;
  const int wm = (wid >> 1) * 64, wn = (wid & 1) * 64;
  const u16* Abz = Ab + (size_t)z * aBatch;
  const u16* BTz = BT + (size_t)z * bBatch;

  v4f acc[4][4];
  #pragma unroll
  for (int mi = 0; mi < 4; mi++)
    #pragma unroll
    for (int ni = 0; ni < 4; ni++)
      acc[mi][ni] = (v4f){0.f, 0.f, 0.f, 0.f};

  for (int k0 = 0; k0 < K; k0 += BK){
    if (AMODE == 0){
      #pragma unroll
      for (int i = 0; i < 4; i++){
        int idx = tid + i * 256;
        int r = idx >> 3, s = idx & 7;
        const float* src = Af + (size_t)(m0 + r) * lda + (k0 + s * 8);
        v4f lo = ((const v4f*)src)[0];
        v4f hi = ((const v4f*)src)[1];
        u32 p0 = (u32)f2bf(lo.x) | ((u32)f2bf(lo.y) << 16);
        u32 p1 = (u32)f2bf(lo.z) | ((u32)f2bf(lo.w) << 16);
        u32 p2 = (u32)f2bf(hi.x) | ((u32)f2bf(hi.y) << 16);
        u32 p3 = (u32)f2bf(hi.z) | ((u32)f2bf(hi.w) << 16);
        *(uint4*)&As[(size_t)idx * 8] = make_uint4(p0, p1, p2, p3);
      }
    } else {
      #pragma unroll
      for (int i = 0; i < 4; i++){
        int idx = tid + i * 256;
        int r = idx >> 3, s = idx & 7;
        int kk = k0 + s * 8;
        const u16* src;
        if (AMODE == 2){
          src = (kk < 1024) ? (Abz + (size_t)(m0 + r) * 1024 + kk)
                            : (A2b + (size_t)(m0 + r) * 1024 + (kk - 1024));
        } else {
          src = Abz + (size_t)(m0 + r) * lda + kk;
        }
        gld_lds16(src, &As[(size_t)idx * 8]);
      }
    }
    #pragma unroll
    for (int i = 0; i < 4; i++){
      int idx = tid + i * 256;
      int r = idx >> 3, s = idx & 7;
      gld_lds16(BTz + (size_t)(n0 + r) * ldb + (k0 + s * 8), &Bs[(size_t)idx * 8]);
    }
    __syncthreads();   // drains vmcnt (global_load_lds) + lgkm before reads
    #pragma unroll
    for (int ks = 0; ks < BK; ks += 32){
      short8 a[4], b[4];
      #pragma unroll
      for (int mi = 0; mi < 4; mi++)
        a[mi] = *(const short8*)&As[(wm + mi * 16 + (lane & 15)) * BK + ks + (lane >> 4) * 8];
      #pragma unroll
      for (int ni = 0; ni < 4; ni++)
        b[ni] = *(const short8*)&Bs[(wn + ni * 16 + (lane & 15)) * BK + ks + (lane >> 4) * 8];
      #pragma unroll
      for (int mi = 0; mi < 4; mi++)
        #pragma unroll
        for (int ni = 0; ni < 4; ni++)
          acc[mi][ni] = __builtin_amdgcn_mfma_f32_16x16x32_bf16(a[mi], b[ni], acc[mi][ni], 0, 0, 0);
    }
    __syncthreads();
  }

  // epilogue: C/D layout col = lane&15, row = (lane>>4)*4 + r  (m89/m91-verified)
  const int lr = (lane >> 4) * 4, lc = lane & 15;
  if (EPI == 0 || EPI == 1){
    u16* C = (u16*)Cout + (size_t)z * cBatch;
    #pragma unroll
    for (int mi = 0; mi < 4; mi++){
      #pragma unroll
      for (int ni = 0; ni < 4; ni++){
        int col = n0 + wn + ni * 16 + lc;
        float bv = (EPI == 0) ? bias[col] : 0.f;
        #pragma unroll
        for (int r = 0; r < 4; r++){
          int row = m0 + wm + mi * 16 + lr + r;
          C[(size_t)row * ldc + col] = f2bf(acc[mi][ni][r] * scale + bv);
        }
      }
    }
  } else if (EPI == 3){
    // transposed store: out[b][col][rowlocal], 4 rows packed per 8B store
    u16* C = (u16*)Cout;
    #pragma unroll
    for (int mi = 0; mi < 4; mi++){
      int rowb = m0 + wm + mi * 16 + lr;       // multiple of 4, single batch
      int b    = rowb >> 11;
      int rloc = rowb & 2047;
      #pragma unroll
      for (int ni = 0; ni < 4; ni++){
        int col = n0 + wn + ni * 16 + lc;
        float bv = bias[col];
        u32 pk[2];
        pk[0] = (u32)f2bf(acc[mi][ni][0] + bv) | ((u32)f2bf(acc[mi][ni][1] + bv) << 16);
        pk[1] = (u32)f2bf(acc[mi][ni][2] + bv) | ((u32)f2bf(acc[mi][ni][3] + bv) << 16);
        *(uint2*)&C[(size_t)b * (1024ull * 2048) + (size_t)col * 2048 + rloc] =
            make_uint2(pk[0], pk[1]);
      }
    }
  } else {
    float* C = (float*)Cout;
    #pragma unroll
    for (int mi = 0; mi < 4; mi++){
      #pragma unroll
      for (int ni = 0; ni < 4; ni++){
        int col = n0 + wn + ni * 16 + lc;
        float bv = bias[col];
        #pragma unroll
        for (int r = 0; r < 4; r++){
          int row = m0 + wm + mi * 16 + lr + r;
          float g  = acc[mi][ni][r] + bv;
          float sg = 1.f / (1.f + __expf(-g));
          float xv = bf2f(xg[(size_t)row * 1024 + col]);
          C[(size_t)row * ldc + col] =
              xv * maskp[row] * sg + q0p[(size_t)row * 1024 + col];
        }
      }
    }
  }
}

// ---------------------------------------------------------------------------
// B=8, L=2048, D=1024. All inputs fp32. Workspace-adaptive pipeline:
//   1. Wq/Wk/Wv/Wg -> bf16 transposed ([N][K]) in ws
//   2. qp/kp proj GEMMs (bf16 out); V proj stores TRANSPOSED -> vpT [b][d][l]
//   3. per chunk of nb batches: S = qp kp^T /32 ; softmax ; x = P V (over kp)
//   4. gate GEMM over concat(qp,x) with fused sigmoid/mask/residual epilogue
// ws: 106 MiB fixed + nb*8 MiB for S (nb picked to fit ws_size; nb=8 -> 170 MiB)
// ---------------------------------------------------------------------------
extern "C" void kernel_launch(void* const* d_in, const int* in_sizes, int n_in,
                              void* d_out, int out_size, void* d_ws, size_t ws_size,
                              hipStream_t stream)
{
  const float* q    = (const float*)d_in[0];
  const float* k    = (const float*)d_in[1];
  const float* v    = (const float*)d_in[2];
  const float* mask = (const float*)d_in[3];
  const float* Wq   = (const float*)d_in[4];
  const float* bq   = (const float*)d_in[5];
  const float* Wk   = (const float*)d_in[6];
  const float* bk   = (const float*)d_in[7];
  const float* Wv   = (const float*)d_in[8];
  const float* bv   = (const float*)d_in[9];
  const float* Wg   = (const float*)d_in[10];
  const float* bg   = (const float*)d_in[11];
  float* out = (float*)d_out;

  char* ws = (char*)d_ws;
  const size_t MB = 1024ull * 1024ull;
  u16* WqT = (u16*)(ws + 0 * MB);    // [1024][1024] bf16
  u16* WkT = (u16*)(ws + 2 * MB);
  u16* WvT = (u16*)(ws + 4 * MB);
  u16* WgT = (u16*)(ws + 6 * MB);    // [1024][2048] bf16
  u16* qp  = (u16*)(ws + 10 * MB);   // [16384][1024] bf16
  u16* kp  = (u16*)(ws + 42 * MB);   // [16384][1024] bf16 ; x overlays per batch
  u16* vpT = (u16*)(ws + 74 * MB);   // [8][1024][2048] bf16 (V proj, transposed)
  u16* S   = (u16*)(ws + 106 * MB);  // [nb][2048][2048] bf16, reused per chunk
  u16* x   = kp;

  // largest nb (batches per S chunk) that fits the workspace; nb=1 best-effort
  int nb = 8;
  while (nb > 1 && 106 * MB + (size_t)nb * 8 * MB > ws_size) nb >>= 1;
  const int nchunks = 8 / nb;

  dim3 B(256);

  // 1. weights -> bf16, transposed to [N][K]
  transpose_w_bf16<<<dim3(16, 16, 1), B, 0, stream>>>(Wq, WqT, 1024, 1024);
  transpose_w_bf16<<<dim3(16, 16, 1), B, 0, stream>>>(Wk, WkT, 1024, 1024);
  transpose_w_bf16<<<dim3(16, 16, 1), B, 0, stream>>>(Wv, WvT, 1024, 1024);
  transpose_w_bf16<<<dim3(32, 16, 1), B, 0, stream>>>(Wg, WgT, 2048, 1024);

  // 2. projections: [16384,1024] x [1024,1024]
  gemm128<0, 0><<<dim3(8, 128, 1), B, 0, stream>>>(q, nullptr, nullptr, WqT, 1024, 1024, 1024,
      qp, 1024, bq, 1.f, 0, 0, 0, nullptr, nullptr, nullptr);
  gemm128<0, 0><<<dim3(8, 128, 1), B, 0, stream>>>(k, nullptr, nullptr, WkT, 1024, 1024, 1024,
      kp, 1024, bk, 1.f, 0, 0, 0, nullptr, nullptr, nullptr);
  gemm128<0, 3><<<dim3(8, 128, 1), B, 0, stream>>>(v, nullptr, nullptr, WvT, 1024, 1024, 1024,
      vpT, 0, bv, 1.f, 0, 0, 0, nullptr, nullptr, nullptr);

  // 3. attention middle, nb batches at a time (S buffer reused across chunks)
  for (int c = 0; c < nchunks; c++){
    const size_t boff = (size_t)c * nb;
    // scores: S[z] = qp[b] kp[b]^T * (1/32); kp rows ARE B^T already
    gemm128<1, 1><<<dim3(16, 16, nb), B, 0, stream>>>(nullptr,
        qp + boff * 2048 * 1024, nullptr, kp + boff * 2048 * 1024,
        1024, 1024, 1024, S, 2048, nullptr, 0.03125f,
        2048ull * 1024, 2048ull * 1024, 2048ull * 2048, nullptr, nullptr, nullptr);
    // softmax over each row of the chunk (in place)
    softmax_rows<<<dim3(nb * 2048, 1, 1), B, 0, stream>>>(S);
    // x[b] = P[z] vp[b]  (B^T = vpT[b]); overwrites kp[b] (dead after scores)
    gemm128<1, 1><<<dim3(8, 16, nb), B, 0, stream>>>(nullptr,
        S, nullptr, vpT + boff * 1024 * 2048,
        2048, 2048, 2048, x + boff * 2048 * 1024, 1024, nullptr, 1.f,
        2048ull * 2048, 1024ull * 2048, 2048ull * 1024, nullptr, nullptr, nullptr);
  }

  // 4. gate GEMM over concat(qp, x) + fused epilogue -> fp32 out
  gemm128<2, 2><<<dim3(8, 128, 1), B, 0, stream>>>(nullptr, qp, x, WgT, 1024, 2048, 2048,
      out, 1024, bg, 1.f, 0, 0, 0, x, mask, q);
}

// Round 4
// 778.768 us; speedup vs baseline: 1.0735x; 1.0735x over previous
//
#include <hip/hip_runtime.h>

typedef unsigned int u32;
typedef unsigned short u16;
using v4f    = __attribute__((ext_vector_type(4))) float;
using short8 = __attribute__((ext_vector_type(8))) short;

#define GAS __attribute__((address_space(1)))
#define LAS __attribute__((address_space(3)))

// ---- bf16 helpers (RNE, matches HW convert; inputs are finite) ----
__device__ __forceinline__ u16 f2bf(float f){
  u32 u = __builtin_bit_cast(u32, f);
  u32 r = (u + 0x7fffu + ((u >> 16) & 1u)) >> 16;
  return (u16)r;
}
__device__ __forceinline__ float bf2f(u16 h){
  u32 u = ((u32)h) << 16;
  return __builtin_bit_cast(float, u);
}

// async global->LDS, 16B per lane. LDS dest must be wave-uniform base + lane*16;
// staging maps thread t -> chunk t + i*256, so per-wave LDS offsets are
// contiguous (the supported pattern).
__device__ __forceinline__ void gld_lds16(const void* g, void* l){
  __builtin_amdgcn_global_load_lds((const GAS u32*)g, (LAS u32*)l, 16, 0, 0);
}

// ---- fp32 -> bf16 bulk convert: 8 elems/thread, no tail (n % 2048 == 0) ----
__global__ __launch_bounds__(256) void cvt_f32_bf16(
    const float* __restrict__ in, u16* __restrict__ out)
{
  const size_t i = ((size_t)blockIdx.x * 256 + threadIdx.x) * 8;
  v4f lo = *(const v4f*)(in + i);
  v4f hi = *(const v4f*)(in + i + 4);
  u32 p0 = (u32)f2bf(lo.x) | ((u32)f2bf(lo.y) << 16);
  u32 p1 = (u32)f2bf(lo.z) | ((u32)f2bf(lo.w) << 16);
  u32 p2 = (u32)f2bf(hi.x) | ((u32)f2bf(hi.y) << 16);
  u32 p3 = (u32)f2bf(hi.z) | ((u32)f2bf(hi.w) << 16);
  *(uint4*)(out + i) = make_uint4(p0, p1, p2, p3);
}

// ---- transpose fp32 [K][N] -> bf16 [N][K] (weights only) ----
__global__ __launch_bounds__(256) void transpose_w_bf16(
    const float* __restrict__ in, u16* __restrict__ out, int K, int N)
{
  __shared__ float t[64][65];   // +1 pad: conflict-free column reads
  const int k0 = blockIdx.x * 64, n0 = blockIdx.y * 64;
  const int tx = threadIdx.x & 63, ty = threadIdx.x >> 6;
  #pragma unroll
  for (int i = 0; i < 16; i++){
    int r = ty + i * 4;
    t[r][tx] = in[(size_t)(k0 + r) * N + (n0 + tx)];
  }
  __syncthreads();
  #pragma unroll
  for (int i = 0; i < 16; i++){
    int r = ty + i * 4;
    out[(size_t)(n0 + r) * K + (k0 + tx)] = f2bf(t[tx][r]);
  }
}

// ---- in-place softmax, one WAVE per 2048-elem row (4 rows/block) ----
// 64 lanes x 32 elems (4 uint4 loads per lane); pure shuffle reduction.
__global__ __launch_bounds__(256) void softmax_rows(u16* __restrict__ S){
  const int lane = threadIdx.x & 63, wid = threadIdx.x >> 6;
  u16* p = S + ((size_t)blockIdx.x * 4 + wid) * 2048;
  uint4 u[4];
  #pragma unroll
  for (int j = 0; j < 4; j++) u[j] = ((const uint4*)p)[lane + j * 64];
  float f[32];
  #pragma unroll
  for (int j = 0; j < 4; j++){
    u32 w4[4] = {u[j].x, u[j].y, u[j].z, u[j].w};
    #pragma unroll
    for (int i = 0; i < 4; i++){
      f[j * 8 + 2*i]     = bf2f((u16)(w4[i] & 0xffffu));
      f[j * 8 + 2*i + 1] = bf2f((u16)(w4[i] >> 16));
    }
  }
  float m = f[0];
  #pragma unroll
  for (int i = 1; i < 32; i++) m = fmaxf(m, f[i]);
  #pragma unroll
  for (int o = 32; o >= 1; o >>= 1) m = fmaxf(m, __shfl_xor(m, o));
  float s = 0.f;
  #pragma unroll
  for (int i = 0; i < 32; i++){ f[i] = __expf(f[i] - m); s += f[i]; }
  #pragma unroll
  for (int o = 32; o >= 1; o >>= 1) s += __shfl_xor(s, o);
  const float inv = 1.f / s;
  #pragma unroll
  for (int j = 0; j < 4; j++){
    u32 w4[4];
    #pragma unroll
    for (int i = 0; i < 4; i++)
      w4[i] = (u32)f2bf(f[j * 8 + 2*i] * inv) |
              ((u32)f2bf(f[j * 8 + 2*i + 1] * inv) << 16);
    ((uint4*)p)[lane + j * 64] = make_uint4(w4[0], w4[1], w4[2], w4[3]);
  }
}

// ---- 128x128x64 bf16 MFMA GEMM: C = A * BT^T (BT is [N][K] row-major) ----
// GROUP-8 swizzle: 8 consecutive blocks share a B-panel, walk 8 A-panels
// (requires gridDim.x pow2 and gridDim.y % 8 == 0 -- true for all launches).
// AMODE: 0 = A fp32 global (convert in staging), 1 = A bf16, 2 = A concat(qp,x) bf16
// EPI:   0 = +bias[col], store bf16        1 = *scale, store bf16
//        2 = gate: out = x*mask*sigmoid(acc+bg) + q0, store fp32
//        3 = +bias[col], store bf16 TRANSPOSED into [batch][col][rowlocal]
//            (batch = row>>11, rowlocal = row&2047; 4 rows packed per 8B store)
template<int AMODE, int EPI>
__global__ __launch_bounds__(256) void gemm128(
    const float* __restrict__ Af,
    const u16* __restrict__ Ab,
    const u16* __restrict__ A2b,
    const u16* __restrict__ BT,
    int lda, int ldb, int K,
    void* __restrict__ Cout, int ldc,
    const float* __restrict__ bias, float scale,
    size_t aBatch, size_t bBatch, size_t cBatch,
    const u16* __restrict__ xg,
    const float* __restrict__ maskp,
    const float* __restrict__ q0p)
{
  constexpr int BM = 128, BN = 128, BK = 64;
  __shared__ __align__(16) u16 As[BM * BK];   // [m][k]
  __shared__ __align__(16) u16 Bs[BN * BK];   // [n][k]  (B^T tile)
  const int z   = blockIdx.z;
  // GROUP-8 swizzle: lin -> (bx, by) with by varying fastest within a group
  const int lin  = blockIdx.y * gridDim.x + blockIdx.x;
  const int l2gx = 31 - __clz((int)gridDim.x);        // gridDim.x is pow2
  const int g    = lin >> (3 + l2gx);
  const int rem  = lin & (((int)gridDim.x << 3) - 1);
  const int m0   = ((g << 3) + (rem & 7)) * BM;
  const int n0   = (rem >> 3) * BN;
  const int tid = threadIdx.x;
  const int lane = tid & 63, wid = tid >> 6;
  const int wm = (wid >> 1) * 64, wn = (wid & 1) * 64;
  const u16* Abz = Ab + (size_t)z * aBatch;
  const u16* BTz = BT + (size_t)z * bBatch;

  v4f acc[4][4];
  #pragma unroll
  for (int mi = 0; mi < 4; mi++)
    #pragma unroll
    for (int ni = 0; ni < 4; ni++)
      acc[mi][ni] = (v4f){0.f, 0.f, 0.f, 0.f};

  for (int k0 = 0; k0 < K; k0 += BK){
    if (AMODE == 0){
      #pragma unroll
      for (int i = 0; i < 4; i++){
        int idx = tid + i * 256;
        int r = idx >> 3, s = idx & 7;
        const float* src = Af + (size_t)(m0 + r) * lda + (k0 + s * 8);
        v4f lo = ((const v4f*)src)[0];
        v4f hi = ((const v4f*)src)[1];
        u32 p0 = (u32)f2bf(lo.x) | ((u32)f2bf(lo.y) << 16);
        u32 p1 = (u32)f2bf(lo.z) | ((u32)f2bf(lo.w) << 16);
        u32 p2 = (u32)f2bf(hi.x) | ((u32)f2bf(hi.y) << 16);
        u32 p3 = (u32)f2bf(hi.z) | ((u32)f2bf(hi.w) << 16);
        *(uint4*)&As[(size_t)idx * 8] = make_uint4(p0, p1, p2, p3);
      }
    } else {
      #pragma unroll
      for (int i = 0; i < 4; i++){
        int idx = tid + i * 256;
        int r = idx >> 3, s = idx & 7;
        int kk = k0 + s * 8;
        const u16* src;
        if (AMODE == 2){
          src = (kk < 1024) ? (Abz + (size_t)(m0 + r) * 1024 + kk)
                            : (A2b + (size_t)(m0 + r) * 1024 + (kk - 1024));
        } else {
          src = Abz + (size_t)(m0 + r) * lda + kk;
        }
        gld_lds16(src, &As[(size_t)idx * 8]);
      }
    }
    #pragma unroll
    for (int i = 0; i < 4; i++){
      int idx = tid + i * 256;
      int r = idx >> 3, s = idx & 7;
      gld_lds16(BTz + (size_t)(n0 + r) * ldb + (k0 + s * 8), &Bs[(size_t)idx * 8]);
    }
    __syncthreads();   // drains vmcnt (global_load_lds) + lgkm before reads
    #pragma unroll
    for (int ks = 0; ks < BK; ks += 32){
      short8 a[4], b[4];
      #pragma unroll
      for (int mi = 0; mi < 4; mi++)
        a[mi] = *(const short8*)&As[(wm + mi * 16 + (lane & 15)) * BK + ks + (lane >> 4) * 8];
      #pragma unroll
      for (int ni = 0; ni < 4; ni++)
        b[ni] = *(const short8*)&Bs[(wn + ni * 16 + (lane & 15)) * BK + ks + (lane >> 4) * 8];
      #pragma unroll
      for (int mi = 0; mi < 4; mi++)
        #pragma unroll
        for (int ni = 0; ni < 4; ni++)
          acc[mi][ni] = __builtin_amdgcn_mfma_f32_16x16x32_bf16(a[mi], b[ni], acc[mi][ni], 0, 0, 0);
    }
    __syncthreads();
  }

  // epilogue: C/D layout col = lane&15, row = (lane>>4)*4 + r  (m89/m91-verified)
  const int lr = (lane >> 4) * 4, lc = lane & 15;
  if (EPI == 0 || EPI == 1){
    u16* C = (u16*)Cout + (size_t)z * cBatch;
    #pragma unroll
    for (int mi = 0; mi < 4; mi++){
      #pragma unroll
      for (int ni = 0; ni < 4; ni++){
        int col = n0 + wn + ni * 16 + lc;
        float bv = (EPI == 0) ? bias[col] : 0.f;
        #pragma unroll
        for (int r = 0; r < 4; r++){
          int row = m0 + wm + mi * 16 + lr + r;
          C[(size_t)row * ldc + col] = f2bf(acc[mi][ni][r] * scale + bv);
        }
      }
    }
  } else if (EPI == 3){
    // transposed store: out[b][col][rowlocal], 4 rows packed per 8B store
    u16* C = (u16*)Cout;
    #pragma unroll
    for (int mi = 0; mi < 4; mi++){
      int rowb = m0 + wm + mi * 16 + lr;       // multiple of 4, single batch
      int b    = rowb >> 11;
      int rloc = rowb & 2047;
      #pragma unroll
      for (int ni = 0; ni < 4; ni++){
        int col = n0 + wn + ni * 16 + lc;
        float bv = bias[col];
        u32 pk[2];
        pk[0] = (u32)f2bf(acc[mi][ni][0] + bv) | ((u32)f2bf(acc[mi][ni][1] + bv) << 16);
        pk[1] = (u32)f2bf(acc[mi][ni][2] + bv) | ((u32)f2bf(acc[mi][ni][3] + bv) << 16);
        *(uint2*)&C[(size_t)b * (1024ull * 2048) + (size_t)col * 2048 + rloc] =
            make_uint2(pk[0], pk[1]);
      }
    }
  } else {
    float* C = (float*)Cout;
    #pragma unroll
    for (int mi = 0; mi < 4; mi++){
      #pragma unroll
      for (int ni = 0; ni < 4; ni++){
        int col = n0 + wn + ni * 16 + lc;
        float bv = bias[col];
        #pragma unroll
        for (int r = 0; r < 4; r++){
          int row = m0 + wm + mi * 16 + lr + r;
          float g  = acc[mi][ni][r] + bv;
          float sg = 1.f / (1.f + __expf(-g));
          float xv = bf2f(xg[(size_t)row * 1024 + col]);
          C[(size_t)row * ldc + col] =
              xv * maskp[row] * sg + q0p[(size_t)row * 1024 + col];
        }
      }
    }
  }
}

// ---------------------------------------------------------------------------
// B=8, L=2048, D=1024. All inputs fp32. Pipeline:
//   1. Wq/Wk/Wv/Wg -> bf16 transposed ([N][K]) in ws
//   2. per tensor: convert fp32->bf16 into tmp, then proj GEMM (async staging);
//      V proj stores TRANSPOSED -> vpT [b][d][l]
//   3. per chunk of nb batches: S = qp kp^T /32 ; softmax ; x = P V (over kp)
//   4. gate GEMM over concat(qp,x) with fused sigmoid/mask/residual epilogue
// ws: 106 MiB fixed + max(32 tmp, nb*8 S) MiB (tmp dies before S is born).
// Falls back to fp32-staging projections if ws < 138 MiB.
// ---------------------------------------------------------------------------
extern "C" void kernel_launch(void* const* d_in, const int* in_sizes, int n_in,
                              void* d_out, int out_size, void* d_ws, size_t ws_size,
                              hipStream_t stream)
{
  const float* q    = (const float*)d_in[0];
  const float* k    = (const float*)d_in[1];
  const float* v    = (const float*)d_in[2];
  const float* mask = (const float*)d_in[3];
  const float* Wq   = (const float*)d_in[4];
  const float* bq   = (const float*)d_in[5];
  const float* Wk   = (const float*)d_in[6];
  const float* bk   = (const float*)d_in[7];
  const float* Wv   = (const float*)d_in[8];
  const float* bv   = (const float*)d_in[9];
  const float* Wg   = (const float*)d_in[10];
  const float* bg   = (const float*)d_in[11];
  float* out = (float*)d_out;

  char* ws = (char*)d_ws;
  const size_t MB = 1024ull * 1024ull;
  u16* WqT = (u16*)(ws + 0 * MB);    // [1024][1024] bf16
  u16* WkT = (u16*)(ws + 2 * MB);
  u16* WvT = (u16*)(ws + 4 * MB);
  u16* WgT = (u16*)(ws + 6 * MB);    // [1024][2048] bf16
  u16* qp  = (u16*)(ws + 10 * MB);   // [16384][1024] bf16
  u16* kp  = (u16*)(ws + 42 * MB);   // [16384][1024] bf16 ; x overlays per batch
  u16* vpT = (u16*)(ws + 74 * MB);   // [8][1024][2048] bf16 (V proj, transposed)
  u16* S   = (u16*)(ws + 106 * MB);  // [nb][2048][2048] bf16, reused per chunk
  u16* tmp = (u16*)(ws + 106 * MB);  // [16384][1024] bf16 input convert scratch
  u16* x   = kp;

  const bool bigws = ws_size >= 138 * MB;
  int nb = 8;
  while (nb > 1 && 106 * MB + (size_t)nb * 8 * MB > ws_size) nb >>= 1;
  const int nchunks = 8 / nb;

  dim3 B(256);

  // 1. weights -> bf16, transposed to [N][K]
  transpose_w_bf16<<<dim3(16, 16, 1), B, 0, stream>>>(Wq, WqT, 1024, 1024);
  transpose_w_bf16<<<dim3(16, 16, 1), B, 0, stream>>>(Wk, WkT, 1024, 1024);
  transpose_w_bf16<<<dim3(16, 16, 1), B, 0, stream>>>(Wv, WvT, 1024, 1024);
  transpose_w_bf16<<<dim3(32, 16, 1), B, 0, stream>>>(Wg, WgT, 2048, 1024);

  // 2. projections: [16384,1024] x [1024,1024]
  if (bigws){
    cvt_f32_bf16<<<dim3(8192), B, 0, stream>>>(q, tmp);
    gemm128<1, 0><<<dim3(8, 128, 1), B, 0, stream>>>(nullptr, tmp, nullptr, WqT,
        1024, 1024, 1024, qp, 1024, bq, 1.f, 0, 0, 0, nullptr, nullptr, nullptr);
    cvt_f32_bf16<<<dim3(8192), B, 0, stream>>>(k, tmp);
    gemm128<1, 0><<<dim3(8, 128, 1), B, 0, stream>>>(nullptr, tmp, nullptr, WkT,
        1024, 1024, 1024, kp, 1024, bk, 1.f, 0, 0, 0, nullptr, nullptr, nullptr);
    cvt_f32_bf16<<<dim3(8192), B, 0, stream>>>(v, tmp);
    gemm128<1, 3><<<dim3(8, 128, 1), B, 0, stream>>>(nullptr, tmp, nullptr, WvT,
        1024, 1024, 1024, vpT, 0, bv, 1.f, 0, 0, 0, nullptr, nullptr, nullptr);
  } else {
    gemm128<0, 0><<<dim3(8, 128, 1), B, 0, stream>>>(q, nullptr, nullptr, WqT,
        1024, 1024, 1024, qp, 1024, bq, 1.f, 0, 0, 0, nullptr, nullptr, nullptr);
    gemm128<0, 0><<<dim3(8, 128, 1), B, 0, stream>>>(k, nullptr, nullptr, WkT,
        1024, 1024, 1024, kp, 1024, bk, 1.f, 0, 0, 0, nullptr, nullptr, nullptr);
    gemm128<0, 3><<<dim3(8, 128, 1), B, 0, stream>>>(v, nullptr, nullptr, WvT,
        1024, 1024, 1024, vpT, 0, bv, 1.f, 0, 0, 0, nullptr, nullptr, nullptr);
  }

  // 3. attention middle, nb batches at a time (S buffer reused across chunks)
  for (int c = 0; c < nchunks; c++){
    const size_t boff = (size_t)c * nb;
    // scores: S[z] = qp[b] kp[b]^T * (1/32); kp rows ARE B^T already
    gemm128<1, 1><<<dim3(16, 16, nb), B, 0, stream>>>(nullptr,
        qp + boff * 2048 * 1024, nullptr, kp + boff * 2048 * 1024,
        1024, 1024, 1024, S, 2048, nullptr, 0.03125f,
        2048ull * 1024, 2048ull * 1024, 2048ull * 2048, nullptr, nullptr, nullptr);
    // softmax: one wave per row, 4 rows per block (in place)
    softmax_rows<<<dim3(nb * 512, 1, 1), B, 0, stream>>>(S);
    // x[b] = P[z] vp[b]  (B^T = vpT[b]); overwrites kp[b] (dead after scores)
    gemm128<1, 1><<<dim3(8, 16, nb), B, 0, stream>>>(nullptr,
        S, nullptr, vpT + boff * 1024 * 2048,
        2048, 2048, 2048, x + boff * 2048 * 1024, 1024, nullptr, 1.f,
        2048ull * 2048, 1024ull * 2048, 2048ull * 1024, nullptr, nullptr, nullptr);
  }

  // 4. gate GEMM over concat(qp, x) + fused epilogue -> fp32 out
  gemm128<2, 2><<<dim3(8, 128, 1), B, 0, stream>>>(nullptr, qp, x, WgT, 1024, 2048, 2048,
      out, 1024, bg, 1.f, 0, 0, 0, x, mask, q);
}